// Round 16
// baseline (370.644 us; speedup 1.0000x reference)
//
#include <hip/hip_runtime.h>

#define NN 20000
#define FF 128
#define HH 128
#define LL 4
#define OO 64
#define EE 640000
#define ET (EE + NN)            // total edges incl self-loops
#define NEG 0.2f
#define NB ((NN + 255) / 256)   // 79 scan blocks
#define NTILES (NN / 16)        // 1250

typedef short bf16x8 __attribute__((ext_vector_type(8)));
typedef float f32x4 __attribute__((ext_vector_type(4)));

__device__ inline ushort f2bf(float f) {  // f32 -> bf16 RNE
    uint u = __float_as_uint(f);
    return (ushort)((u + 0x7fffu + ((u >> 16) & 1u)) >> 16);
}

// ---------------- CSR build (dst-grouped, launch-invariant) ----------------

__global__ void k_init_counters(int* __restrict__ counters) {
    int i = blockIdx.x * 256 + threadIdx.x;
    if (i < NN) counters[i] = 1;  // self-loop pre-counted
}

__global__ void k_hist(const int* __restrict__ dst, int* __restrict__ counters) {
    int e = blockIdx.x * 256 + threadIdx.x;
    if (e < EE) atomicAdd(&counters[dst[e]], 1);
}

__global__ void k_partial(const int* __restrict__ counters, int* __restrict__ partials) {
    __shared__ int ws[4];
    int t = threadIdx.x;
    int i = blockIdx.x * 256 + t;
    int c = (i < NN) ? counters[i] : 0;
    #pragma unroll
    for (int off = 32; off; off >>= 1) c += __shfl_xor(c, off);
    if ((t & 63) == 0) ws[t >> 6] = c;
    __syncthreads();
    if (t == 0) partials[blockIdx.x] = ws[0] + ws[1] + ws[2] + ws[3];
}

__global__ void k_scan_small(const int* __restrict__ partials, int* __restrict__ offsets) {
    __shared__ int sp[128];
    int t = threadIdx.x;
    int v = (t < NB) ? partials[t] : 0;
    sp[t] = v;
    __syncthreads();
    for (int off = 1; off < 128; off <<= 1) {
        int u = (t >= off) ? sp[t - off] : 0;
        __syncthreads();
        sp[t] += u;
        __syncthreads();
    }
    if (t < NB) offsets[t] = sp[t] - v;  // exclusive
}

__global__ void k_apply(const int* __restrict__ counters, const int* __restrict__ offsets,
                        int* __restrict__ row_off, int* __restrict__ cursor,
                        int2* __restrict__ edges) {
    __shared__ int sc[256];
    int t = threadIdx.x;
    int i = blockIdx.x * 256 + t;
    int c = (i < NN) ? counters[i] : 0;
    sc[t] = c;
    __syncthreads();
    for (int off = 1; off < 256; off <<= 1) {
        int u = (t >= off) ? sc[t - off] : 0;
        __syncthreads();
        sc[t] += u;
        __syncthreads();
    }
    int incl = sc[t];
    int base = offsets[blockIdx.x];
    if (i < NN) {
        int excl = base + incl - c;
        row_off[i] = excl;
        cursor[i] = excl + 1;       // slot 0 taken by self-loop
        edges[excl] = make_int2(i, i);  // self-loop edge first
        if (i == NN - 1) row_off[NN] = base + incl;
    }
}

__global__ void k_scatter(const int* __restrict__ src, const int* __restrict__ dst,
                          int* __restrict__ cursor, int2* __restrict__ edges) {
    int e = blockIdx.x * 256 + threadIdx.x;
    if (e < EE) {
        int d = dst[e];
        int pidx = atomicAdd(&cursor[d], 1);
        edges[pidx] = make_int2(src[e], d);   // one 8B scatter (one line/edge)
    }
}

// ---------------- W conversion: f32 [k][n] -> bf16 hi/lo transposed [n][k] ----------------

__global__ void k_convw(const float* __restrict__ Ws, const float* __restrict__ Wout,
                        ushort* __restrict__ wh, ushort* __restrict__ wl) {
    int idx = blockIdx.x * 256 + threadIdx.x;
    const int per_l = HH * 128;
    float v;
    if (idx < LL * per_l) {
        int l = idx / per_l, rem = idx % per_l;
        int n = rem >> 7, k = rem & 127;
        v = Ws[(size_t)l * 128 * HH + (size_t)k * HH + n];
    } else {
        int j = idx - LL * per_l;
        if (j >= OO * 128) return;
        int n = j >> 7, k = j & 127;
        v = Wout[(size_t)k * OO + n];
    }
    ushort h = f2bf(v);
    float hf = __uint_as_float((uint)h << 16);
    wh[idx] = h;
    wl[idx] = f2bf(v - hf);
}

// ---------------- wa precompute: wa[l][0][k] = (W_l @ a_s)[k]; [1][k] for a_d ----

__global__ void k_wa(const float* __restrict__ Ws, const float* __restrict__ attS,
                     const float* __restrict__ attD, float* __restrict__ wa) {
    int t = blockIdx.x * 256 + threadIdx.x;
    if (t >= LL * 256) return;
    int l = t >> 8, rem = t & 255, which = rem >> 7, k = rem & 127;
    const float* wrow = Ws + (size_t)l * 128 * HH + (size_t)k * HH;
    const float* av = (which ? attD : attS) + l * HH;
    float s = 0.f;
    #pragma unroll 4
    for (int n = 0; n < HH; n++) s += wrow[n] * av[n];
    wa[l * 256 + which * 128 + k] = s;
}

// ---------------- edge weights: pe[e] = {p, src} ----------------

__global__ void k_ew(const float* __restrict__ asv, const float* __restrict__ adv,
                     const int2* __restrict__ edges, float2* __restrict__ pe) {
    int e = blockIdx.x * 256 + threadIdx.x;
    if (e >= ET) return;
    int2 ed = edges[e];
    float ad_ = adv[ed.y];
    float ls = asv[ed.x] + ad_;  ls = (ls >= 0.f) ? ls : NEG * ls;
    float ld = asv[ed.y] + ad_;  ld = (ld >= 0.f) ? ld : NEG * ld;
    float2 o;
    o.x = __expf(ls - ld);
    o.y = __int_as_float(ed.x);
    pe[e] = o;
}

// ---------------- agg: ONE QUARTER per launch (L2-resident 2.625MB gather set) ------------
// zq quarter-major [4][NN][32]. Wave: c4 = lane&7 (float4 within quarter row),
// ep = lane>>3 (8 parallel edges); 2-deep unroll = 16 edges in flight.
// Reduce over ep via shfl_xor 8/16/32. s recomputed per pass (identical value).
// h row-major [NN][128]; each pass writes its 128B quarter of the row.

__global__ __launch_bounds__(256)
void k_aggq(const float* __restrict__ zq, const float2* __restrict__ pe,
            const int* __restrict__ row_off, const float* __restrict__ bias,
            float* __restrict__ h, int q) {
    int node = blockIdx.x * 4 + (threadIdx.x >> 6);
    int l64 = threadIdx.x & 63;
    if (node >= NN) return;
    int c4 = l64 & 7, ep = l64 >> 3;
    int beg = row_off[node], end = row_off[node + 1], lim = end - 1;
    const float* qb = zq + (size_t)q * NN * 32;

    float4 acc = make_float4(0.f, 0.f, 0.f, 0.f);
    float s = 0.f;
    for (int e = beg + ep; e < end; e += 16) {   // edges e, e+8
        int i1 = min(e + 8, lim);
        float2 q0 = pe[e], q1 = pe[i1];
        int s0 = __float_as_int(q0.y), s1 = __float_as_int(q1.y);
        float p0 = q0.x;
        float p1 = (e + 8 < end) ? q1.x : 0.f;
        float4 z0 = *(const float4*)(qb + (size_t)s0 * 32 + c4 * 4);
        float4 z1 = *(const float4*)(qb + (size_t)s1 * 32 + c4 * 4);
        s += p0 + p1;
        acc.x += p0 * z0.x + p1 * z1.x;
        acc.y += p0 * z0.y + p1 * z1.y;
        acc.z += p0 * z0.z + p1 * z1.z;
        acc.w += p0 * z0.w + p1 * z1.w;
    }

    #pragma unroll
    for (int off = 8; off < 64; off <<= 1) {
        acc.x += __shfl_xor(acc.x, off);
        acc.y += __shfl_xor(acc.y, off);
        acc.z += __shfl_xor(acc.z, off);
        acc.w += __shfl_xor(acc.w, off);
        s     += __shfl_xor(s, off);
    }

    if (ep == 0) {
        float inv = 1.f / (s + 1e-16f);
        float4 b = *(const float4*)(bias + q * 32 + c4 * 4);
        float4 o;
        o.x = fmaxf(acc.x * inv + b.x, 0.f);
        o.y = fmaxf(acc.y * inv + b.y, 0.f);
        o.z = fmaxf(acc.z * inv + b.z, 0.f);
        o.w = fmaxf(acc.w * inv + b.w, 0.f);
        *(float4*)&h[(size_t)node * 128 + q * 32 + c4 * 4] = o;
    }
}

// ---------------- GEMM: 1250 x 256-thr blocks; A staged once in LDS; 4 waves x 32 cols ----
// PACKED: write channels quarter-major [4][NN][32]. ALPHAS epilogue via wa (wave 0).

template <int NCOL, bool BIAS, bool ALPHAS, bool PACKED>
__global__ __launch_bounds__(256)
void k_gemm2(const float* __restrict__ A, const ushort* __restrict__ wh,
             const ushort* __restrict__ wl, const float* __restrict__ bias,
             float* __restrict__ C, const float* __restrict__ wa,
             float* __restrict__ as_o, float* __restrict__ ad_o) {
    __shared__ float h[16][132];
    int t = threadIdx.x;
    int row0 = blockIdx.x * 16;
    for (int i = t; i < 512; i += 256) {
        int r = i >> 5, c4 = (i & 31) << 2;
        *(float4*)&h[r][c4] = *(const float4*)&A[(size_t)(row0 + r) * 128 + c4];
    }
    __syncthreads();

    int wid = t >> 6, l64 = t & 63;
    constexpr int CT = NCOL / 32;
    if (wid >= CT) return;
    int lr = l64 & 15, lg = l64 >> 4;
    int col0 = wid * 32;

    f32x4 af0[4], af1[4];
    #pragma unroll
    for (int s = 0; s < 4; s++) {
        af0[s] = *(const f32x4*)&h[lr][s * 32 + lg * 8];
        af1[s] = *(const f32x4*)&h[lr][s * 32 + lg * 8 + 4];
    }
    bf16x8 ah[4], al[4];
    #pragma unroll
    for (int s = 0; s < 4; s++) {
        #pragma unroll
        for (int j = 0; j < 8; j++) {
            float v = (j < 4) ? af0[s][j] : af1[s][j - 4];
            ushort hb = f2bf(v);
            float hf = __uint_as_float((uint)hb << 16);
            ah[s][j] = (short)hb;
            al[s][j] = (short)f2bf(v - hf);
        }
    }

    f32x4 acc[2] = {{0.f, 0.f, 0.f, 0.f}, {0.f, 0.f, 0.f, 0.f}};
    #pragma unroll
    for (int s = 0; s < 4; s++) {
        #pragma unroll
        for (int nt = 0; nt < 2; nt++) {
            int woff = (col0 + nt * 16 + lr) * 128 + s * 32 + lg * 8;
            bf16x8 bh = *(const bf16x8*)(wh + woff);
            bf16x8 bl = *(const bf16x8*)(wl + woff);
            acc[nt] = __builtin_amdgcn_mfma_f32_16x16x32_bf16(ah[s], bh, acc[nt], 0, 0, 0);
            acc[nt] = __builtin_amdgcn_mfma_f32_16x16x32_bf16(ah[s], bl, acc[nt], 0, 0, 0);
            acc[nt] = __builtin_amdgcn_mfma_f32_16x16x32_bf16(al[s], bh, acc[nt], 0, 0, 0);
        }
    }

    int orow = lg * 4;
    #pragma unroll
    for (int nt = 0; nt < 2; nt++) {
        int c = col0 + nt * 16 + lr;
        #pragma unroll
        for (int r = 0; r < 4; r++) {
            float v = acc[nt][r];
            if (BIAS) v += bias[c];
            if (PACKED)
                C[((size_t)(c >> 5) * NN + (row0 + orow + r)) * 32 + (c & 31)] = v;
            else
                C[(size_t)(row0 + orow + r) * NCOL + c] = v;
        }
    }

    if constexpr (ALPHAS) {
        if (wid == 0) {
            float ps = 0.f, pd = 0.f;
            #pragma unroll
            for (int s = 0; s < 4; s++) {
                #pragma unroll
                for (int j = 0; j < 8; j++) {
                    float v = (j < 4) ? af0[s][j] : af1[s][j - 4];
                    int k = s * 32 + lg * 8 + j;
                    ps += v * wa[k];
                    pd += v * wa[128 + k];
                }
            }
            ps += __shfl_xor(ps, 16);  pd += __shfl_xor(pd, 16);
            ps += __shfl_xor(ps, 32);  pd += __shfl_xor(pd, 32);
            if (lg == 0) {
                as_o[row0 + lr] = ps;
                ad_o[row0 + lr] = pd;
            }
        }
    }
}

// ---------------- launch ----------------

extern "C" void kernel_launch(void* const* d_in, const int* in_sizes, int n_in,
                              void* d_out, int out_size, void* d_ws, size_t ws_size,
                              hipStream_t stream) {
    const float* x      = (const float*)d_in[0];
    const int*   ei     = (const int*)d_in[1];
    const float* Ws     = (const float*)d_in[2];
    const float* attS   = (const float*)d_in[3];
    const float* attD   = (const float*)d_in[4];
    const float* biases = (const float*)d_in[5];
    const float* W_out  = (const float*)d_in[6];
    const float* b_out  = (const float*)d_in[7];
    float* out = (float*)d_out;

    const int* srcp = ei;
    const int* dstp = ei + EE;

    char* w = (char*)d_ws;
    auto take = [&](size_t bytes) {
        char* p = w;
        w += (bytes + 15) & ~(size_t)15;
        return p;
    };
    float*  za         = (float*)take((size_t)NN * HH * 4);   // quarter-major
    float*  zbv        = (float*)take((size_t)NN * HH * 4);   // quarter-major
    float*  hbuf       = (float*)take((size_t)NN * HH * 4);   // row-major
    float*  asa        = (float*)take((size_t)NN * 4);
    float*  ada        = (float*)take((size_t)NN * 4);
    float*  asb        = (float*)take((size_t)NN * 4);
    float*  adb        = (float*)take((size_t)NN * 4);
    int*    counters   = (int*)take((size_t)NN * 4);
    int*    row_off    = (int*)take((size_t)(NN + 1) * 4);
    int*    cursor     = (int*)take((size_t)NN * 4);
    int2*   edges      = (int2*)take((size_t)ET * 8);
    float2* pebuf      = (float2*)take((size_t)ET * 8);
    int*    partials   = (int*)take((size_t)NB * 4);
    int*    offsets    = (int*)take((size_t)NB * 4);
    const int WTOT = LL * HH * 128 + OO * 128;   // 73728
    ushort* whbuf      = (ushort*)take((size_t)WTOT * 2);
    ushort* wlbuf      = (ushort*)take((size_t)WTOT * 2);
    float*  wabuf      = (float*)take((size_t)LL * 256 * 4);

    // CSR build + weight prep
    k_init_counters<<<(NN + 255) / 256, 256, 0, stream>>>(counters);
    k_hist<<<(EE + 255) / 256, 256, 0, stream>>>(dstp, counters);
    k_partial<<<NB, 256, 0, stream>>>(counters, partials);
    k_scan_small<<<1, 128, 0, stream>>>(partials, offsets);
    k_apply<<<NB, 256, 0, stream>>>(counters, offsets, row_off, cursor, edges);
    k_scatter<<<(EE + 255) / 256, 256, 0, stream>>>(srcp, dstp, cursor, edges);
    k_convw<<<(WTOT + 255) / 256, 256, 0, stream>>>(Ws, W_out, whbuf, wlbuf);
    k_wa<<<(LL * 256 + 255) / 256, 256, 0, stream>>>(Ws, attS, attD, wabuf);

    const int agg_blocks = (NN + 3) / 4;      // 5000
    const int ew_blocks  = (ET + 255) / 256;  // 2579

    // layer 0: z0 = x @ W0 (+alphas), packed quarter-major
    k_gemm2<HH, false, true, true><<<NTILES, 256, 0, stream>>>(
        x, whbuf, wlbuf, nullptr, za, wabuf, asa, ada);

    // layers 1..3: ew + 4x aggq + gemm (+alphas), z double-buffer
    const float* zi[3]  = {za, zbv, za};
    float*       zo[3]  = {zbv, za, zbv};
    const float* asi[3] = {asa, asb, asa};
    const float* adi[3] = {ada, adb, ada};
    float*       aso[3] = {asb, asa, asb};
    float*       ado[3] = {adb, ada, adb};
    for (int l = 0; l < 3; l++) {
        k_ew<<<ew_blocks, 256, 0, stream>>>(asi[l], adi[l], edges, pebuf);
        for (int q = 0; q < 4; q++)
            k_aggq<<<agg_blocks, 256, 0, stream>>>(zi[l], pebuf, row_off,
                                                   biases + l * HH, hbuf, q);
        k_gemm2<HH, false, true, true><<<NTILES, 256, 0, stream>>>(
            hbuf, whbuf + (size_t)(l + 1) * HH * 128, wlbuf + (size_t)(l + 1) * HH * 128,
            nullptr, zo[l], wabuf + (l + 1) * 256, aso[l], ado[l]);
    }

    // final layer: ew + 4x aggq(z3) + out-projection with bias (row-major out)
    k_ew<<<ew_blocks, 256, 0, stream>>>(asb, adb, edges, pebuf);
    for (int q = 0; q < 4; q++)
        k_aggq<<<agg_blocks, 256, 0, stream>>>(zbv, pebuf, row_off,
                                               biases + 3 * HH, hbuf, q);
    k_gemm2<OO, true, false, false><<<NTILES, 256, 0, stream>>>(
        hbuf, whbuf + (size_t)LL * HH * 128, wlbuf + (size_t)LL * HH * 128,
        b_out, out, nullptr, nullptr, nullptr);
}

// Round 17
// 314.006 us; speedup vs baseline: 1.1804x; 1.1804x over previous
//
#include <hip/hip_runtime.h>

#define NN 20000
#define FF 128
#define HH 128
#define LL 4
#define OO 64
#define EE 640000
#define ET (EE + NN)            // total edges incl self-loops
#define NEG 0.2f
#define NB ((NN + 255) / 256)   // 79 scan blocks
#define NTILES (NN / 16)        // 1250

typedef short bf16x8 __attribute__((ext_vector_type(8)));
typedef float f32x4 __attribute__((ext_vector_type(4)));

__device__ inline ushort f2bf(float f) {  // f32 -> bf16 RNE
    uint u = __float_as_uint(f);
    return (ushort)((u + 0x7fffu + ((u >> 16) & 1u)) >> 16);
}

// ---------------- CSR build (dst-grouped, launch-invariant) ----------------
// counters memset to 0 by host; self-loop accounted as +1 in partial/apply.

__global__ void k_hist(const int* __restrict__ dst, int* __restrict__ counters) {
    int e = blockIdx.x * 256 + threadIdx.x;
    if (e < EE) atomicAdd(&counters[dst[e]], 1);
}

__global__ void k_partial(const int* __restrict__ counters, int* __restrict__ partials) {
    __shared__ int ws[4];
    int t = threadIdx.x;
    int i = blockIdx.x * 256 + t;
    int c = (i < NN) ? counters[i] + 1 : 0;   // +1 self-loop
    #pragma unroll
    for (int off = 32; off; off >>= 1) c += __shfl_xor(c, off);
    if ((t & 63) == 0) ws[t >> 6] = c;
    __syncthreads();
    if (t == 0) partials[blockIdx.x] = ws[0] + ws[1] + ws[2] + ws[3];
}

__global__ void k_scan_small(const int* __restrict__ partials, int* __restrict__ offsets) {
    __shared__ int sp[128];
    int t = threadIdx.x;
    int v = (t < NB) ? partials[t] : 0;
    sp[t] = v;
    __syncthreads();
    for (int off = 1; off < 128; off <<= 1) {
        int u = (t >= off) ? sp[t - off] : 0;
        __syncthreads();
        sp[t] += u;
        __syncthreads();
    }
    if (t < NB) offsets[t] = sp[t] - v;  // exclusive
}

__global__ void k_apply(const int* __restrict__ counters, const int* __restrict__ offsets,
                        int* __restrict__ row_off, int* __restrict__ cursor,
                        int2* __restrict__ edges) {
    __shared__ int sc[256];
    int t = threadIdx.x;
    int i = blockIdx.x * 256 + t;
    int c = (i < NN) ? counters[i] + 1 : 0;   // +1 self-loop
    sc[t] = c;
    __syncthreads();
    for (int off = 1; off < 256; off <<= 1) {
        int u = (t >= off) ? sc[t - off] : 0;
        __syncthreads();
        sc[t] += u;
        __syncthreads();
    }
    int incl = sc[t];
    int base = offsets[blockIdx.x];
    if (i < NN) {
        int excl = base + incl - c;
        row_off[i] = excl;
        cursor[i] = excl + 1;           // slot 0 taken by self-loop
        edges[excl] = make_int2(i, i);  // self-loop edge first
        if (i == NN - 1) row_off[NN] = base + incl;
    }
}

__global__ void k_scatter(const int* __restrict__ src, const int* __restrict__ dst,
                          int* __restrict__ cursor, int2* __restrict__ edges) {
    int e = blockIdx.x * 256 + threadIdx.x;
    if (e < EE) {
        int d = dst[e];
        int pidx = atomicAdd(&cursor[d], 1);
        edges[pidx] = make_int2(src[e], d);   // one 8B scatter (one line/edge)
    }
}

// ---------------- W conversion: f32 [k][n] -> bf16 hi/lo transposed [n][k] ----------------

__global__ void k_convw(const float* __restrict__ Ws, const float* __restrict__ Wout,
                        ushort* __restrict__ wh, ushort* __restrict__ wl) {
    int idx = blockIdx.x * 256 + threadIdx.x;
    const int per_l = HH * 128;
    float v;
    if (idx < LL * per_l) {
        int l = idx / per_l, rem = idx % per_l;
        int n = rem >> 7, k = rem & 127;
        v = Ws[(size_t)l * 128 * HH + (size_t)k * HH + n];
    } else {
        int j = idx - LL * per_l;
        if (j >= OO * 128) return;
        int n = j >> 7, k = j & 127;
        v = Wout[(size_t)k * OO + n];
    }
    ushort h = f2bf(v);
    float hf = __uint_as_float((uint)h << 16);
    wh[idx] = h;
    wl[idx] = f2bf(v - hf);
}

// ---------------- wa precompute: wa[l][0][k] = (W_l @ a_s)[k]; [1][k] for a_d ----

__global__ void k_wa(const float* __restrict__ Ws, const float* __restrict__ attS,
                     const float* __restrict__ attD, float* __restrict__ wa) {
    int t = blockIdx.x * 256 + threadIdx.x;
    if (t >= LL * 256) return;
    int l = t >> 8, rem = t & 255, which = rem >> 7, k = rem & 127;
    const float* wrow = Ws + (size_t)l * 128 * HH + (size_t)k * HH;
    const float* av = (which ? attD : attS) + l * HH;
    float s = 0.f;
    #pragma unroll 4
    for (int n = 0; n < HH; n++) s += wrow[n] * av[n];
    wa[l * 256 + which * 128 + k] = s;
}

// ---------------- agg: wave per node, inline p (edges 8B load; as[] L2-hot 80KB) ----------
// 256-thr blocks, 4 nodes/block (5000 blocks). Lane-group g takes contiguous 8-edge
// runs; 16 edges in flight. p = exp(leaky(as[src]+adn) - mx), mx = self-loop logit
// (slot 0 -> p_self = 1, s >= 1). h = relu(acc/s + bias) -> global row-major.

__global__ __launch_bounds__(256)
void k_agg(const float* __restrict__ z, const int2* __restrict__ edges,
           const int* __restrict__ row_off, const float* __restrict__ asv,
           const float* __restrict__ adv, const float* __restrict__ bias,
           float* __restrict__ h) {
    int node = blockIdx.x * 4 + (threadIdx.x >> 6);
    int l64 = threadIdx.x & 63;
    if (node >= NN) return;
    int g = l64 >> 5, cl = l64 & 31;
    int beg = row_off[node], end = row_off[node + 1], lim = end - 1;
    float adn = adv[node];
    float lself = asv[node] + adn;
    float mx = (lself >= 0.f) ? lself : NEG * lself;
    const float4* zb = (const float4*)z;

    float4 acc = make_float4(0.f, 0.f, 0.f, 0.f);
    float s = 0.f;
    for (int e = beg + g * 8; e < end; e += 16) {
        int i1 = min(e + 1, lim), i2 = min(e + 2, lim), i3 = min(e + 3, lim);
        int i4 = min(e + 4, lim), i5 = min(e + 5, lim), i6 = min(e + 6, lim), i7 = min(e + 7, lim);
        int s0 = edges[e].x,  s1 = edges[i1].x, s2 = edges[i2].x, s3 = edges[i3].x;
        int s4 = edges[i4].x, s5 = edges[i5].x, s6 = edges[i6].x, s7 = edges[i7].x;
        float l0 = asv[s0] + adn, l1 = asv[s1] + adn, l2 = asv[s2] + adn, l3 = asv[s3] + adn;
        float l4 = asv[s4] + adn, l5 = asv[s5] + adn, l6 = asv[s6] + adn, l7 = asv[s7] + adn;
        l0 = (l0 >= 0.f) ? l0 : NEG * l0;  l1 = (l1 >= 0.f) ? l1 : NEG * l1;
        l2 = (l2 >= 0.f) ? l2 : NEG * l2;  l3 = (l3 >= 0.f) ? l3 : NEG * l3;
        l4 = (l4 >= 0.f) ? l4 : NEG * l4;  l5 = (l5 >= 0.f) ? l5 : NEG * l5;
        l6 = (l6 >= 0.f) ? l6 : NEG * l6;  l7 = (l7 >= 0.f) ? l7 : NEG * l7;
        float4 z0 = zb[(size_t)s0 * 32 + cl];
        float4 z1 = zb[(size_t)s1 * 32 + cl];
        float4 z2 = zb[(size_t)s2 * 32 + cl];
        float4 z3 = zb[(size_t)s3 * 32 + cl];
        float4 z4 = zb[(size_t)s4 * 32 + cl];
        float4 z5 = zb[(size_t)s5 * 32 + cl];
        float4 z6 = zb[(size_t)s6 * 32 + cl];
        float4 z7 = zb[(size_t)s7 * 32 + cl];
        float p0 = __expf(l0 - mx);
        float p1 = (e + 1 < end) ? __expf(l1 - mx) : 0.f;
        float p2 = (e + 2 < end) ? __expf(l2 - mx) : 0.f;
        float p3 = (e + 3 < end) ? __expf(l3 - mx) : 0.f;
        float p4 = (e + 4 < end) ? __expf(l4 - mx) : 0.f;
        float p5 = (e + 5 < end) ? __expf(l5 - mx) : 0.f;
        float p6 = (e + 6 < end) ? __expf(l6 - mx) : 0.f;
        float p7 = (e + 7 < end) ? __expf(l7 - mx) : 0.f;
        s += ((p0 + p1) + (p2 + p3)) + ((p4 + p5) + (p6 + p7));
        acc.x += (p0 * z0.x + p1 * z1.x + p2 * z2.x + p3 * z3.x)
               + (p4 * z4.x + p5 * z5.x + p6 * z6.x + p7 * z7.x);
        acc.y += (p0 * z0.y + p1 * z1.y + p2 * z2.y + p3 * z3.y)
               + (p4 * z4.y + p5 * z5.y + p6 * z6.y + p7 * z7.y);
        acc.z += (p0 * z0.z + p1 * z1.z + p2 * z2.z + p3 * z3.z)
               + (p4 * z4.z + p5 * z5.z + p6 * z6.z + p7 * z7.z);
        acc.w += (p0 * z0.w + p1 * z1.w + p2 * z2.w + p3 * z3.w)
               + (p4 * z4.w + p5 * z5.w + p6 * z6.w + p7 * z7.w);
    }

    acc.x += __shfl_xor(acc.x, 32);
    acc.y += __shfl_xor(acc.y, 32);
    acc.z += __shfl_xor(acc.z, 32);
    acc.w += __shfl_xor(acc.w, 32);
    s     += __shfl_xor(s, 32);

    if (g == 0) {
        float inv = 1.f / (s + 1e-16f);
        float4 b = ((const float4*)bias)[cl];
        float4 o;
        o.x = fmaxf(acc.x * inv + b.x, 0.f);
        o.y = fmaxf(acc.y * inv + b.y, 0.f);
        o.z = fmaxf(acc.z * inv + b.z, 0.f);
        o.w = fmaxf(acc.w * inv + b.w, 0.f);
        ((float4*)h)[(size_t)node * 32 + cl] = o;
    }
}

// ---------------- GEMM: 1250 x 256-thr blocks; A staged once in LDS; 4 waves x 32 cols ----
// bf16x3 MFMA; ALPHAS epilogue via wa (wave 0). Frag maps per guide §3 (m89).

template <int NCOL, bool BIAS, bool ALPHAS>
__global__ __launch_bounds__(256)
void k_gemm2(const float* __restrict__ A, const ushort* __restrict__ wh,
             const ushort* __restrict__ wl, const float* __restrict__ bias,
             float* __restrict__ C, const float* __restrict__ wa,
             float* __restrict__ as_o, float* __restrict__ ad_o) {
    __shared__ float h[16][132];
    int t = threadIdx.x;
    int row0 = blockIdx.x * 16;
    for (int i = t; i < 512; i += 256) {
        int r = i >> 5, c4 = (i & 31) << 2;
        *(float4*)&h[r][c4] = *(const float4*)&A[(size_t)(row0 + r) * 128 + c4];
    }
    __syncthreads();

    int wid = t >> 6, l64 = t & 63;
    constexpr int CT = NCOL / 32;
    if (wid >= CT) return;
    int lr = l64 & 15, lg = l64 >> 4;
    int col0 = wid * 32;

    f32x4 af0[4], af1[4];
    #pragma unroll
    for (int s = 0; s < 4; s++) {
        af0[s] = *(const f32x4*)&h[lr][s * 32 + lg * 8];
        af1[s] = *(const f32x4*)&h[lr][s * 32 + lg * 8 + 4];
    }
    bf16x8 ah[4], al[4];
    #pragma unroll
    for (int s = 0; s < 4; s++) {
        #pragma unroll
        for (int j = 0; j < 8; j++) {
            float v = (j < 4) ? af0[s][j] : af1[s][j - 4];
            ushort hb = f2bf(v);
            float hf = __uint_as_float((uint)hb << 16);
            ah[s][j] = (short)hb;
            al[s][j] = (short)f2bf(v - hf);
        }
    }

    f32x4 acc[2] = {{0.f, 0.f, 0.f, 0.f}, {0.f, 0.f, 0.f, 0.f}};
    #pragma unroll
    for (int s = 0; s < 4; s++) {
        #pragma unroll
        for (int nt = 0; nt < 2; nt++) {
            int woff = (col0 + nt * 16 + lr) * 128 + s * 32 + lg * 8;
            bf16x8 bh = *(const bf16x8*)(wh + woff);
            bf16x8 bl = *(const bf16x8*)(wl + woff);
            acc[nt] = __builtin_amdgcn_mfma_f32_16x16x32_bf16(ah[s], bh, acc[nt], 0, 0, 0);
            acc[nt] = __builtin_amdgcn_mfma_f32_16x16x32_bf16(ah[s], bl, acc[nt], 0, 0, 0);
            acc[nt] = __builtin_amdgcn_mfma_f32_16x16x32_bf16(al[s], bh, acc[nt], 0, 0, 0);
        }
    }

    int orow = lg * 4;
    #pragma unroll
    for (int nt = 0; nt < 2; nt++) {
        int c = col0 + nt * 16 + lr;
        #pragma unroll
        for (int r = 0; r < 4; r++) {
            float v = acc[nt][r];
            if (BIAS) v += bias[c];
            C[(size_t)(row0 + orow + r) * NCOL + c] = v;
        }
    }

    if constexpr (ALPHAS) {
        if (wid == 0) {
            float ps = 0.f, pd = 0.f;
            #pragma unroll
            for (int s = 0; s < 4; s++) {
                #pragma unroll
                for (int j = 0; j < 8; j++) {
                    float v = (j < 4) ? af0[s][j] : af1[s][j - 4];
                    int k = s * 32 + lg * 8 + j;
                    ps += v * wa[k];
                    pd += v * wa[128 + k];
                }
            }
            ps += __shfl_xor(ps, 16);  pd += __shfl_xor(pd, 16);
            ps += __shfl_xor(ps, 32);  pd += __shfl_xor(pd, 32);
            if (lg == 0) {
                as_o[row0 + lr] = ps;
                ad_o[row0 + lr] = pd;
            }
        }
    }
}

// ---------------- launch ----------------

extern "C" void kernel_launch(void* const* d_in, const int* in_sizes, int n_in,
                              void* d_out, int out_size, void* d_ws, size_t ws_size,
                              hipStream_t stream) {
    const float* x      = (const float*)d_in[0];
    const int*   ei     = (const int*)d_in[1];
    const float* Ws     = (const float*)d_in[2];
    const float* attS   = (const float*)d_in[3];
    const float* attD   = (const float*)d_in[4];
    const float* biases = (const float*)d_in[5];
    const float* W_out  = (const float*)d_in[6];
    const float* b_out  = (const float*)d_in[7];
    float* out = (float*)d_out;

    const int* srcp = ei;
    const int* dstp = ei + EE;

    char* w = (char*)d_ws;
    auto take = [&](size_t bytes) {
        char* p = w;
        w += (bytes + 15) & ~(size_t)15;
        return p;
    };
    float*  za         = (float*)take((size_t)NN * HH * 4);
    float*  zbv        = (float*)take((size_t)NN * HH * 4);
    float*  hbuf       = (float*)take((size_t)NN * HH * 4);
    float*  asa        = (float*)take((size_t)NN * 4);
    float*  ada        = (float*)take((size_t)NN * 4);
    float*  asb        = (float*)take((size_t)NN * 4);
    float*  adb        = (float*)take((size_t)NN * 4);
    int*    counters   = (int*)take((size_t)NN * 4);
    int*    row_off    = (int*)take((size_t)(NN + 1) * 4);
    int*    cursor     = (int*)take((size_t)NN * 4);
    int2*   edges      = (int2*)take((size_t)ET * 8);
    int*    partials   = (int*)take((size_t)NB * 4);
    int*    offsets    = (int*)take((size_t)NB * 4);
    const int WTOT = LL * HH * 128 + OO * 128;   // 73728
    ushort* whbuf      = (ushort*)take((size_t)WTOT * 2);
    ushort* wlbuf      = (ushort*)take((size_t)WTOT * 2);
    float*  wabuf      = (float*)take((size_t)LL * 256 * 4);

    // CSR build + weight prep
    hipMemsetAsync(counters, 0, (size_t)NN * 4, stream);
    k_hist<<<(EE + 255) / 256, 256, 0, stream>>>(dstp, counters);
    k_partial<<<NB, 256, 0, stream>>>(counters, partials);
    k_scan_small<<<1, 128, 0, stream>>>(partials, offsets);
    k_apply<<<NB, 256, 0, stream>>>(counters, offsets, row_off, cursor, edges);
    k_scatter<<<(EE + 255) / 256, 256, 0, stream>>>(srcp, dstp, cursor, edges);
    k_convw<<<(WTOT + 255) / 256, 256, 0, stream>>>(Ws, W_out, whbuf, wlbuf);
    k_wa<<<(LL * 256 + 255) / 256, 256, 0, stream>>>(Ws, attS, attD, wabuf);

    const int agg_blocks = (NN + 3) / 4;      // 5000

    // layer 0: z0 = x @ W0 (+alphas)
    k_gemm2<HH, false, true><<<NTILES, 256, 0, stream>>>(
        x, whbuf, wlbuf, nullptr, za, wabuf, asa, ada);

    // layers 1..3: agg (inline p) + gemm (+alphas), z double-buffer
    const float* zi[3]  = {za, zbv, za};
    float*       zo[3]  = {zbv, za, zbv};
    const float* asi[3] = {asa, asb, asa};
    const float* adi[3] = {ada, adb, ada};
    float*       aso[3] = {asb, asa, asb};
    float*       ado[3] = {adb, ada, adb};
    for (int l = 0; l < 3; l++) {
        k_agg<<<agg_blocks, 256, 0, stream>>>(zi[l], edges, row_off, asi[l], adi[l],
                                              biases + l * HH, hbuf);
        k_gemm2<HH, false, true><<<NTILES, 256, 0, stream>>>(
            hbuf, whbuf + (size_t)(l + 1) * HH * 128, wlbuf + (size_t)(l + 1) * HH * 128,
            nullptr, zo[l], wabuf + (l + 1) * 256, aso[l], ado[l]);
    }

    // final layer: agg(z3) + out-projection with bias
    k_agg<<<agg_blocks, 256, 0, stream>>>(zbv, edges, row_off, asb, adb,
                                          biases + 3 * HH, hbuf);
    k_gemm2<OO, true, false><<<NTILES, 256, 0, stream>>>(
        hbuf, whbuf + (size_t)LL * HH * 128, wlbuf + (size_t)LL * HH * 128,
        b_out, out, nullptr, nullptr, nullptr);
}

// Round 18
// 309.678 us; speedup vs baseline: 1.1969x; 1.0140x over previous
//
#include <hip/hip_runtime.h>

#define NN 20000
#define FF 128
#define HH 128
#define LL 4
#define OO 64
#define EE 640000
#define ET (EE + NN)            // total edges incl self-loops
#define NEG 0.2f
#define NB ((NN + 255) / 256)   // 79 scan blocks
#define NTILES (NN / 16)        // 1250

typedef short bf16x8 __attribute__((ext_vector_type(8)));
typedef float f32x4 __attribute__((ext_vector_type(4)));

__device__ inline ushort f2bf(float f) {  // f32 -> bf16 RNE
    uint u = __float_as_uint(f);
    return (ushort)((u + 0x7fffu + ((u >> 16) & 1u)) >> 16);
}

// ---------------- CSR build (dst-grouped, launch-invariant) ----------------
// counters memset to 0 by host; self-loop accounted as +1 in partial/apply.

__global__ void k_hist(const int* __restrict__ dst, int* __restrict__ counters) {
    int e = blockIdx.x * 256 + threadIdx.x;
    if (e < EE) atomicAdd(&counters[dst[e]], 1);
}

__global__ void k_partial(const int* __restrict__ counters, int* __restrict__ partials) {
    __shared__ int ws[4];
    int t = threadIdx.x;
    int i = blockIdx.x * 256 + t;
    int c = (i < NN) ? counters[i] + 1 : 0;   // +1 self-loop
    #pragma unroll
    for (int off = 32; off; off >>= 1) c += __shfl_xor(c, off);
    if ((t & 63) == 0) ws[t >> 6] = c;
    __syncthreads();
    if (t == 0) partials[blockIdx.x] = ws[0] + ws[1] + ws[2] + ws[3];
}

__global__ void k_scan_small(const int* __restrict__ partials, int* __restrict__ offsets) {
    __shared__ int sp[128];
    int t = threadIdx.x;
    int v = (t < NB) ? partials[t] : 0;
    sp[t] = v;
    __syncthreads();
    for (int off = 1; off < 128; off <<= 1) {
        int u = (t >= off) ? sp[t - off] : 0;
        __syncthreads();
        sp[t] += u;
        __syncthreads();
    }
    if (t < NB) offsets[t] = sp[t] - v;  // exclusive
}

__global__ void k_apply(const int* __restrict__ counters, const int* __restrict__ offsets,
                        int* __restrict__ row_off, int* __restrict__ cursor,
                        int* __restrict__ srcs) {
    __shared__ int sc[256];
    int t = threadIdx.x;
    int i = blockIdx.x * 256 + t;
    int c = (i < NN) ? counters[i] + 1 : 0;   // +1 self-loop
    sc[t] = c;
    __syncthreads();
    for (int off = 1; off < 256; off <<= 1) {
        int u = (t >= off) ? sc[t - off] : 0;
        __syncthreads();
        sc[t] += u;
        __syncthreads();
    }
    int incl = sc[t];
    int base = offsets[blockIdx.x];
    if (i < NN) {
        int excl = base + incl - c;
        row_off[i] = excl;
        cursor[i] = excl + 1;   // slot 0 taken by self-loop
        srcs[excl] = i;         // self-loop edge first
        if (i == NN - 1) row_off[NN] = base + incl;
    }
}

__global__ void k_scatter(const int* __restrict__ src, const int* __restrict__ dst,
                          int* __restrict__ cursor, int* __restrict__ srcs) {
    int e = blockIdx.x * 256 + threadIdx.x;
    if (e < EE) {
        int pidx = atomicAdd(&cursor[dst[e]], 1);
        srcs[pidx] = src[e];    // one 4B scatter per edge
    }
}

// ---------------- W conversion: f32 [k][n] -> bf16 hi/lo transposed [n][k] ----------------

__global__ void k_convw(const float* __restrict__ Ws, const float* __restrict__ Wout,
                        ushort* __restrict__ wh, ushort* __restrict__ wl) {
    int idx = blockIdx.x * 256 + threadIdx.x;
    const int per_l = HH * 128;
    float v;
    if (idx < LL * per_l) {
        int l = idx / per_l, rem = idx % per_l;
        int n = rem >> 7, k = rem & 127;
        v = Ws[(size_t)l * 128 * HH + (size_t)k * HH + n];
    } else {
        int j = idx - LL * per_l;
        if (j >= OO * 128) return;
        int n = j >> 7, k = j & 127;
        v = Wout[(size_t)k * OO + n];
    }
    ushort h = f2bf(v);
    float hf = __uint_as_float((uint)h << 16);
    wh[idx] = h;
    wl[idx] = f2bf(v - hf);
}

// ---------------- wa precompute: wa[l][0][k] = (W_l @ a_s)[k]; [1][k] for a_d ----

__global__ void k_wa(const float* __restrict__ Ws, const float* __restrict__ attS,
                     const float* __restrict__ attD, float* __restrict__ wa) {
    int t = blockIdx.x * 256 + threadIdx.x;
    if (t >= LL * 256) return;
    int l = t >> 8, rem = t & 255, which = rem >> 7, k = rem & 127;
    const float* wrow = Ws + (size_t)l * 128 * HH + (size_t)k * HH;
    const float* av = (which ? attD : attS) + l * HH;
    float s = 0.f;
    #pragma unroll 4
    for (int n = 0; n < HH; n++) s += wrow[n] * av[n];
    wa[l * 256 + which * 128 + k] = s;
}

// ---------------- agg: wave per node, inline p (srcs 4B stream; as[] L2-hot 80KB) ---------
// 256-thr blocks, 4 nodes/block (5000 blocks). Lane-group g takes contiguous 8-edge
// runs; 16 edges in flight. p = exp(leaky(as[src]+adn) - mx), mx = self-loop logit
// (slot 0 -> p_self = 1, s >= 1). h = relu(acc/s + bias) -> global row-major.

__global__ __launch_bounds__(256)
void k_agg(const float* __restrict__ z, const int* __restrict__ srcs,
           const int* __restrict__ row_off, const float* __restrict__ asv,
           const float* __restrict__ adv, const float* __restrict__ bias,
           float* __restrict__ h) {
    int node = blockIdx.x * 4 + (threadIdx.x >> 6);
    int l64 = threadIdx.x & 63;
    if (node >= NN) return;
    int g = l64 >> 5, cl = l64 & 31;
    int beg = row_off[node], end = row_off[node + 1], lim = end - 1;
    float adn = adv[node];
    float lself = asv[node] + adn;
    float mx = (lself >= 0.f) ? lself : NEG * lself;
    const float4* zb = (const float4*)z;

    float4 acc = make_float4(0.f, 0.f, 0.f, 0.f);
    float s = 0.f;
    for (int e = beg + g * 8; e < end; e += 16) {
        int i1 = min(e + 1, lim), i2 = min(e + 2, lim), i3 = min(e + 3, lim);
        int i4 = min(e + 4, lim), i5 = min(e + 5, lim), i6 = min(e + 6, lim), i7 = min(e + 7, lim);
        int s0 = srcs[e],  s1 = srcs[i1], s2 = srcs[i2], s3 = srcs[i3];
        int s4 = srcs[i4], s5 = srcs[i5], s6 = srcs[i6], s7 = srcs[i7];
        float l0 = asv[s0] + adn, l1 = asv[s1] + adn, l2 = asv[s2] + adn, l3 = asv[s3] + adn;
        float l4 = asv[s4] + adn, l5 = asv[s5] + adn, l6 = asv[s6] + adn, l7 = asv[s7] + adn;
        l0 = (l0 >= 0.f) ? l0 : NEG * l0;  l1 = (l1 >= 0.f) ? l1 : NEG * l1;
        l2 = (l2 >= 0.f) ? l2 : NEG * l2;  l3 = (l3 >= 0.f) ? l3 : NEG * l3;
        l4 = (l4 >= 0.f) ? l4 : NEG * l4;  l5 = (l5 >= 0.f) ? l5 : NEG * l5;
        l6 = (l6 >= 0.f) ? l6 : NEG * l6;  l7 = (l7 >= 0.f) ? l7 : NEG * l7;
        float4 z0 = zb[(size_t)s0 * 32 + cl];
        float4 z1 = zb[(size_t)s1 * 32 + cl];
        float4 z2 = zb[(size_t)s2 * 32 + cl];
        float4 z3 = zb[(size_t)s3 * 32 + cl];
        float4 z4 = zb[(size_t)s4 * 32 + cl];
        float4 z5 = zb[(size_t)s5 * 32 + cl];
        float4 z6 = zb[(size_t)s6 * 32 + cl];
        float4 z7 = zb[(size_t)s7 * 32 + cl];
        float p0 = __expf(l0 - mx);
        float p1 = (e + 1 < end) ? __expf(l1 - mx) : 0.f;
        float p2 = (e + 2 < end) ? __expf(l2 - mx) : 0.f;
        float p3 = (e + 3 < end) ? __expf(l3 - mx) : 0.f;
        float p4 = (e + 4 < end) ? __expf(l4 - mx) : 0.f;
        float p5 = (e + 5 < end) ? __expf(l5 - mx) : 0.f;
        float p6 = (e + 6 < end) ? __expf(l6 - mx) : 0.f;
        float p7 = (e + 7 < end) ? __expf(l7 - mx) : 0.f;
        s += ((p0 + p1) + (p2 + p3)) + ((p4 + p5) + (p6 + p7));
        acc.x += (p0 * z0.x + p1 * z1.x + p2 * z2.x + p3 * z3.x)
               + (p4 * z4.x + p5 * z5.x + p6 * z6.x + p7 * z7.x);
        acc.y += (p0 * z0.y + p1 * z1.y + p2 * z2.y + p3 * z3.y)
               + (p4 * z4.y + p5 * z5.y + p6 * z6.y + p7 * z7.y);
        acc.z += (p0 * z0.z + p1 * z1.z + p2 * z2.z + p3 * z3.z)
               + (p4 * z4.z + p5 * z5.z + p6 * z6.z + p7 * z7.z);
        acc.w += (p0 * z0.w + p1 * z1.w + p2 * z2.w + p3 * z3.w)
               + (p4 * z4.w + p5 * z5.w + p6 * z6.w + p7 * z7.w);
    }

    acc.x += __shfl_xor(acc.x, 32);
    acc.y += __shfl_xor(acc.y, 32);
    acc.z += __shfl_xor(acc.z, 32);
    acc.w += __shfl_xor(acc.w, 32);
    s     += __shfl_xor(s, 32);

    if (g == 0) {
        float inv = 1.f / (s + 1e-16f);
        float4 b = ((const float4*)bias)[cl];
        float4 o;
        o.x = fmaxf(acc.x * inv + b.x, 0.f);
        o.y = fmaxf(acc.y * inv + b.y, 0.f);
        o.z = fmaxf(acc.z * inv + b.z, 0.f);
        o.w = fmaxf(acc.w * inv + b.w, 0.f);
        ((float4*)h)[(size_t)node * 32 + cl] = o;
    }
}

// ---------------- GEMM: 1250 x 256-thr blocks; A staged once in LDS; 4 waves x 32 cols ----
// bf16x3 MFMA; ALPHAS epilogue via wa (wave 0). Frag maps per guide §3 (m89).

template <int NCOL, bool BIAS, bool ALPHAS>
__global__ __launch_bounds__(256)
void k_gemm2(const float* __restrict__ A, const ushort* __restrict__ wh,
             const ushort* __restrict__ wl, const float* __restrict__ bias,
             float* __restrict__ C, const float* __restrict__ wa,
             float* __restrict__ as_o, float* __restrict__ ad_o) {
    __shared__ float h[16][132];
    int t = threadIdx.x;
    int row0 = blockIdx.x * 16;
    for (int i = t; i < 512; i += 256) {
        int r = i >> 5, c4 = (i & 31) << 2;
        *(float4*)&h[r][c4] = *(const float4*)&A[(size_t)(row0 + r) * 128 + c4];
    }
    __syncthreads();

    int wid = t >> 6, l64 = t & 63;
    constexpr int CT = NCOL / 32;
    if (wid >= CT) return;
    int lr = l64 & 15, lg = l64 >> 4;
    int col0 = wid * 32;

    f32x4 af0[4], af1[4];
    #pragma unroll
    for (int s = 0; s < 4; s++) {
        af0[s] = *(const f32x4*)&h[lr][s * 32 + lg * 8];
        af1[s] = *(const f32x4*)&h[lr][s * 32 + lg * 8 + 4];
    }
    bf16x8 ah[4], al[4];
    #pragma unroll
    for (int s = 0; s < 4; s++) {
        #pragma unroll
        for (int j = 0; j < 8; j++) {
            float v = (j < 4) ? af0[s][j] : af1[s][j - 4];
            ushort hb = f2bf(v);
            float hf = __uint_as_float((uint)hb << 16);
            ah[s][j] = (short)hb;
            al[s][j] = (short)f2bf(v - hf);
        }
    }

    f32x4 acc[2] = {{0.f, 0.f, 0.f, 0.f}, {0.f, 0.f, 0.f, 0.f}};
    #pragma unroll
    for (int s = 0; s < 4; s++) {
        #pragma unroll
        for (int nt = 0; nt < 2; nt++) {
            int woff = (col0 + nt * 16 + lr) * 128 + s * 32 + lg * 8;
            bf16x8 bh = *(const bf16x8*)(wh + woff);
            bf16x8 bl = *(const bf16x8*)(wl + woff);
            acc[nt] = __builtin_amdgcn_mfma_f32_16x16x32_bf16(ah[s], bh, acc[nt], 0, 0, 0);
            acc[nt] = __builtin_amdgcn_mfma_f32_16x16x32_bf16(ah[s], bl, acc[nt], 0, 0, 0);
            acc[nt] = __builtin_amdgcn_mfma_f32_16x16x32_bf16(al[s], bh, acc[nt], 0, 0, 0);
        }
    }

    int orow = lg * 4;
    #pragma unroll
    for (int nt = 0; nt < 2; nt++) {
        int c = col0 + nt * 16 + lr;
        #pragma unroll
        for (int r = 0; r < 4; r++) {
            float v = acc[nt][r];
            if (BIAS) v += bias[c];
            C[(size_t)(row0 + orow + r) * NCOL + c] = v;
        }
    }

    if constexpr (ALPHAS) {
        if (wid == 0) {
            float ps = 0.f, pd = 0.f;
            #pragma unroll
            for (int s = 0; s < 4; s++) {
                #pragma unroll
                for (int j = 0; j < 8; j++) {
                    float v = (j < 4) ? af0[s][j] : af1[s][j - 4];
                    int k = s * 32 + lg * 8 + j;
                    ps += v * wa[k];
                    pd += v * wa[128 + k];
                }
            }
            ps += __shfl_xor(ps, 16);  pd += __shfl_xor(pd, 16);
            ps += __shfl_xor(ps, 32);  pd += __shfl_xor(pd, 32);
            if (lg == 0) {
                as_o[row0 + lr] = ps;
                ad_o[row0 + lr] = pd;
            }
        }
    }
}

// ---------------- launch ----------------

extern "C" void kernel_launch(void* const* d_in, const int* in_sizes, int n_in,
                              void* d_out, int out_size, void* d_ws, size_t ws_size,
                              hipStream_t stream) {
    const float* x      = (const float*)d_in[0];
    const int*   ei     = (const int*)d_in[1];
    const float* Ws     = (const float*)d_in[2];
    const float* attS   = (const float*)d_in[3];
    const float* attD   = (const float*)d_in[4];
    const float* biases = (const float*)d_in[5];
    const float* W_out  = (const float*)d_in[6];
    const float* b_out  = (const float*)d_in[7];
    float* out = (float*)d_out;

    const int* srcp = ei;
    const int* dstp = ei + EE;

    char* w = (char*)d_ws;
    auto take = [&](size_t bytes) {
        char* p = w;
        w += (bytes + 15) & ~(size_t)15;
        return p;
    };
    float*  za         = (float*)take((size_t)NN * HH * 4);
    float*  zbv        = (float*)take((size_t)NN * HH * 4);
    float*  hbuf       = (float*)take((size_t)NN * HH * 4);
    float*  asa        = (float*)take((size_t)NN * 4);
    float*  ada        = (float*)take((size_t)NN * 4);
    float*  asb        = (float*)take((size_t)NN * 4);
    float*  adb        = (float*)take((size_t)NN * 4);
    int*    counters   = (int*)take((size_t)NN * 4);
    int*    row_off    = (int*)take((size_t)(NN + 1) * 4);
    int*    cursor     = (int*)take((size_t)NN * 4);
    int*    srcs       = (int*)take((size_t)ET * 4);
    int*    partials   = (int*)take((size_t)NB * 4);
    int*    offsets    = (int*)take((size_t)NB * 4);
    const int WTOT = LL * HH * 128 + OO * 128;   // 73728
    ushort* whbuf      = (ushort*)take((size_t)WTOT * 2);
    ushort* wlbuf      = (ushort*)take((size_t)WTOT * 2);
    float*  wabuf      = (float*)take((size_t)LL * 256 * 4);

    // CSR build + weight prep
    hipMemsetAsync(counters, 0, (size_t)NN * 4, stream);
    k_hist<<<(EE + 255) / 256, 256, 0, stream>>>(dstp, counters);
    k_partial<<<NB, 256, 0, stream>>>(counters, partials);
    k_scan_small<<<1, 128, 0, stream>>>(partials, offsets);
    k_apply<<<NB, 256, 0, stream>>>(counters, offsets, row_off, cursor, srcs);
    k_scatter<<<(EE + 255) / 256, 256, 0, stream>>>(srcp, dstp, cursor, srcs);
    k_convw<<<(WTOT + 255) / 256, 256, 0, stream>>>(Ws, W_out, whbuf, wlbuf);
    k_wa<<<(LL * 256 + 255) / 256, 256, 0, stream>>>(Ws, attS, attD, wabuf);

    const int agg_blocks = (NN + 3) / 4;      // 5000

    // layer 0: z0 = x @ W0 (+alphas)
    k_gemm2<HH, false, true><<<NTILES, 256, 0, stream>>>(
        x, whbuf, wlbuf, nullptr, za, wabuf, asa, ada);

    // layers 1..3: agg (inline p) + gemm (+alphas), z double-buffer
    const float* zi[3]  = {za, zbv, za};
    float*       zo[3]  = {zbv, za, zbv};
    const float* asi[3] = {asa, asb, asa};
    const float* adi[3] = {ada, adb, ada};
    float*       aso[3] = {asb, asa, asb};
    float*       ado[3] = {adb, ada, adb};
    for (int l = 0; l < 3; l++) {
        k_agg<<<agg_blocks, 256, 0, stream>>>(zi[l], srcs, row_off, asi[l], adi[l],
                                              biases + l * HH, hbuf);
        k_gemm2<HH, false, true><<<NTILES, 256, 0, stream>>>(
            hbuf, whbuf + (size_t)(l + 1) * HH * 128, wlbuf + (size_t)(l + 1) * HH * 128,
            nullptr, zo[l], wabuf + (l + 1) * 256, aso[l], ado[l]);
    }

    // final layer: agg(z3) + out-projection with bias
    k_agg<<<agg_blocks, 256, 0, stream>>>(zbv, srcs, row_off, asb, adb,
                                          biases + 3 * HH, hbuf);
    k_gemm2<OO, true, false><<<NTILES, 256, 0, stream>>>(
        hbuf, whbuf + (size_t)LL * HH * 128, wlbuf + (size_t)LL * HH * 128,
        b_out, out, nullptr, nullptr, nullptr);
}